// Round 5
// baseline (224.982 us; speedup 1.0000x reference)
//
#include <hip/hip_runtime.h>
#include <cstdint>

#define N 2048
#define NH 8
#define DI 32
#define DOUT 32
#define BATCH 4
#define LOG2E 1.44269504088896340736f

typedef float f32x4 __attribute__((ext_vector_type(4)));
typedef __bf16 bf16x8 __attribute__((ext_vector_type(8)));

__device__ __forceinline__ unsigned short f2bf(float f) {
    unsigned u = __float_as_uint(f);
    u = u + 0x7fffu + ((u >> 16) & 1u);
    return (unsigned short)(u >> 16);
}

// Deterministic per-block row-max of xj_s[0..2047]. Max is order-independent
// in value (no rounding), so k_rowsum and k_main get identical M for a g.
__device__ __forceinline__ float rowmax2048(const float* xj_s, int tid, float* red) {
    float m = fmaxf(fmaxf(xj_s[tid], xj_s[tid + 256]),
                    fmaxf(xj_s[tid + 512], xj_s[tid + 768]));
    m = fmaxf(m, fmaxf(fmaxf(xj_s[tid + 1024], xj_s[tid + 1280]),
                       fmaxf(xj_s[tid + 1536], xj_s[tid + 1792])));
#pragma unroll
    for (int off = 32; off >= 1; off >>= 1) m = fmaxf(m, __shfl_xor(m, off, 64));
    if ((tid & 63) == 0) red[tid >> 6] = m;
    __syncthreads();
    return fmaxf(fmaxf(red[0], red[1]), fmaxf(red[2], red[3]));
}

// ---------------- K1: fused prep (blocks 0..255) + pack (blocks 256..8447) ----------------
__global__ __launch_bounds__(256) void k_prep_pack(
    const float* __restrict__ x, const float* __restrict__ att_w,
    const int* __restrict__ adj, float* __restrict__ xi, float* __restrict__ xj,
    unsigned short* __restrict__ xhB, unsigned char* __restrict__ adjb) {
    if (blockIdx.x >= 256) {
        // ---- pack path: adj int32 -> bitmask, 8 elems -> 1 byte per thread ----
        int t = (blockIdx.x - 256) * 256 + threadIdx.x;
        const int4* p = (const int4*)adj + (size_t)t * 2;
        int4 a = p[0], b = p[1];
        unsigned byte = (a.x != 0) | ((a.y != 0) << 1) | ((a.z != 0) << 2) | ((a.w != 0) << 3)
                      | ((b.x != 0) << 4) | ((b.y != 0) << 5) | ((b.z != 0) << 6) | ((b.w != 0) << 7);
        adjb[t] = (unsigned char)byte;
        return;
    }
    // ---- prep path: xi, xj, xh B-fragments ----
    int g = blockIdx.x >> 3, chunk = blockIdx.x & 7;
    int b = g >> 3, h = g & 7;
    __shared__ float aw[2 * DI];
    if (threadIdx.x < 2 * DI) aw[threadIdx.x] = att_w[threadIdx.x];
    __syncthreads();

    int i = chunk * 256 + threadIdx.x;
    const float* xr = x + ((size_t)b * N + i) * (NH * DI) + h * DI;
    float si = 0.f, sj = 0.f;
#pragma unroll
    for (int d = 0; d < DI; ++d) {
        float v = xr[d];
        si += v * aw[d];
        sj += v * aw[DI + d];
    }
    xi[g * N + i] = si;
    xj[g * N + i] = sj;

    // B-fragment layout for mfma_f32_16x16x32_bf16 (verified round 1):
    // tiles indexed [g][jt(64)][dh(2)][lane(64)][r(8)]
    for (int t = 0; t < 4; ++t) {
        int item = t * 256 + threadIdx.x;
        int lane = item & 63;
        int dh = (item >> 6) & 1;
        int jt = chunk * 8 + (item >> 7);
        int d = dh * 16 + (lane & 15);
        int j0 = jt * 32 + (lane >> 4) * 8;
        union { unsigned short u[8]; uint4 v; } f;
#pragma unroll
        for (int r = 0; r < 8; ++r) {
            float v = x[((size_t)b * N + j0 + r) * (NH * DI) + h * DI + d];
            f.u[r] = f2bf(v);
        }
        *(uint4*)(xhB + ((((size_t)g * 64 + jt) * 2 + dh) * 64 + lane) * 8) = f.v;
    }
}

// ---------------- K2: row-wise softmax denominators (compute-only) ----------------
__global__ __launch_bounds__(256, 4) void k_rowsum(
    const unsigned* __restrict__ adjp, const float* __restrict__ xi_g,
    const float* __restrict__ xj_g, float* __restrict__ srow) {
    int g = blockIdx.x >> 5;
    int it = blockIdx.x & 31;
    int ab = g & 3;
    int tid = threadIdx.x;
    int w = tid >> 6, l = tid & 63;
    int qg = l >> 4, lr = l & 15;

    __shared__ float xj_s[N];
    __shared__ unsigned adj_s[64][65];
    __shared__ float red[4];

    {
        const float4* src = (const float4*)(xj_g + (size_t)g * N);
        float4* dst = (float4*)xj_s;
        dst[tid] = src[tid];
        dst[256 + tid] = src[256 + tid];
    }
    {
        int row = tid >> 2, seg = tid & 3;
        const uint4* src = (const uint4*)(adjp + (((size_t)ab * N) + it * 64 + row) * 64 + seg * 16);
#pragma unroll
        for (int q = 0; q < 4; ++q) {
            uint4 v = src[q];
            unsigned* dst = &adj_s[row][seg * 16 + q * 4];
            dst[0] = v.x; dst[1] = v.y; dst[2] = v.z; dst[3] = v.w;
        }
    }
    __syncthreads();
    float xjm = rowmax2048(xj_s, tid, red);

    int iloc = w * 16 + lr;
    int i = it * 64 + iloc;
    float xiv = xi_g[(size_t)g * N + i];
    float vM = xiv + xjm;
    float M = fmaxf(vM, 0.01f * vM);
    float nMl = -M * LOG2E;

    float ssum = 0.f;
    for (int jt = 0; jt < 64; ++jt) {
        unsigned byte = (adj_s[iloc][jt] >> (qg * 8)) & 0xffu;
        int j0 = jt * 32 + qg * 8;
        f32x4 xa = *(const f32x4*)&xj_s[j0];
        f32x4 xb4 = *(const f32x4*)&xj_s[j0 + 4];
#pragma unroll
        for (int r = 0; r < 8; ++r) {
            float xjv = (r < 4) ? xa[r] : xb4[r - 4];
            float sc = xiv + xjv;
            sc = fmaxf(sc, 0.01f * sc);
            float p = __builtin_amdgcn_exp2f(fmaf(sc, LOG2E, nMl));
            ssum += ((byte >> r) & 1u) ? p : 0.f;
        }
    }
    ssum += __shfl_xor(ssum, 16, 64);
    ssum += __shfl_xor(ssum, 32, 64);
    if (qg == 0) srow[(size_t)g * N + i] = ssum;
}

// ---------------- K3: single-pass fused main kernel ----------------
// Register double-buffer for xhB fragments: loads for jt+1 issue at the top of
// iteration jt (~400 VALU cycles before use), MFMAs consume last iteration's
// regs (vmcnt wait never drains the att store queue), stores issue last.
__global__ __launch_bounds__(256, 4) void k_main(
    const unsigned* __restrict__ adjp, const float* __restrict__ xi_g,
    const float* __restrict__ xj_g, const float* __restrict__ srow,
    const unsigned short* __restrict__ xhB, const float* __restrict__ fc_w,
    const float* __restrict__ fc_b, float* __restrict__ out0, float* __restrict__ att) {
    int g = blockIdx.x >> 5;
    int it = blockIdx.x & 31;
    int b = g >> 3, h = g & 7, ab = g & 3;
    int tid = threadIdx.x;
    int w = tid >> 6, l = tid & 63;
    int qg = l >> 4, lr = l & 15;

    __shared__ float xj_s[N];
    __shared__ unsigned adj_s[64][65];
    __shared__ float red[4];
    __shared__ float fcw_s[32][33];
    __shared__ float fcb_s[32];
    __shared__ float agg_s[64][33];

    {
        const float4* src = (const float4*)(xj_g + (size_t)g * N);
        float4* dst = (float4*)xj_s;
        dst[tid] = src[tid];
        dst[256 + tid] = src[256 + tid];
    }
    {
        int row = tid >> 2, seg = tid & 3;
        const uint4* src = (const uint4*)(adjp + (((size_t)ab * N) + it * 64 + row) * 64 + seg * 16);
#pragma unroll
        for (int q = 0; q < 4; ++q) {
            uint4 v = src[q];
            unsigned* dst = &adj_s[row][seg * 16 + q * 4];
            dst[0] = v.x; dst[1] = v.y; dst[2] = v.z; dst[3] = v.w;
        }
    }
    if (tid < 32) fcb_s[tid] = fc_b[tid];
    {
        float4 v = ((const float4*)fc_w)[tid];
        int row = tid >> 3, c0 = (tid & 7) * 4;
        fcw_s[row][c0 + 0] = v.x; fcw_s[row][c0 + 1] = v.y;
        fcw_s[row][c0 + 2] = v.z; fcw_s[row][c0 + 3] = v.w;
    }
    __syncthreads();
    float xjm = rowmax2048(xj_s, tid, red);   // identical value to k_rowsum's M

    int iloc = w * 16 + lr;
    int i = it * 64 + iloc;
    float xiv = xi_g[(size_t)g * N + i];
    float vM = xiv + xjm;
    float M = fmaxf(vM, 0.01f * vM);
    float nMl = -M * LOG2E;
    float invA = 1.0f / srow[(size_t)g * N + i];

    f32x4 acc0 = {0.f, 0.f, 0.f, 0.f}, acc1 = {0.f, 0.f, 0.f, 0.f};
    const unsigned short* xb = xhB + (size_t)g * 64 * 2 * 64 * 8;
    float* arow = att + ((size_t)g * N + i) * N;

    // prologue: load jt=0 fragments
    const bf16x8* bp0 = (const bf16x8*)(xb + ((size_t)l) * 8);
    bf16x8 b0 = bp0[0];
    bf16x8 b1 = bp0[64];

    for (int jt = 0; jt < 64; ++jt) {
        // prefetch next iteration's fragments (wraps to 0 on last iter; harmless)
        int jn = (jt + 1) & 63;
        const bf16x8* bpn = (const bf16x8*)(xb + (((size_t)jn * 2) * 64 + l) * 8);
        bf16x8 nb0 = bpn[0];
        bf16x8 nb1 = bpn[64];

        unsigned byte = (adj_s[iloc][jt] >> (qg * 8)) & 0xffu;
        int j0 = jt * 32 + qg * 8;
        f32x4 xa = *(const f32x4*)&xj_s[j0];
        f32x4 xb4 = *(const f32x4*)&xj_s[j0 + 4];
        f32x4 o0, o1;
        bf16x8 af;
#pragma unroll
        for (int r = 0; r < 8; ++r) {
            float xjv = (r < 4) ? xa[r] : xb4[r - 4];
            float sc = xiv + xjv;
            sc = fmaxf(sc, 0.01f * sc);
            float p = __builtin_amdgcn_exp2f(fmaf(sc, LOG2E, nMl)) * invA;
            float av = ((byte >> r) & 1u) ? p : 0.f;
            if (r < 4) o0[r] = av; else o1[r - 4] = av;
            af[r] = (__bf16)av;
        }
        // MFMAs consume fragments loaded LAST iteration -> wait is long satisfied
        acc0 = __builtin_amdgcn_mfma_f32_16x16x32_bf16(af, b0, acc0, 0, 0, 0);
        acc1 = __builtin_amdgcn_mfma_f32_16x16x32_bf16(af, b1, acc1, 0, 0, 0);
        // stores last: pure fire-and-forget, nothing ever waits on them
        *(f32x4*)&arow[j0] = o0;
        *(f32x4*)&arow[j0 + 4] = o1;
        b0 = nb0;
        b1 = nb1;
    }

    // acc is already normalized (A-fragment carried e*invA)
    {
        int r0 = w * 16 + qg * 4;
#pragma unroll
        for (int r = 0; r < 4; ++r) {
            agg_s[r0 + r][lr] = acc0[r];
            agg_s[r0 + r][16 + lr] = acc1[r];
        }
    }
    __syncthreads();
    {
        int orow = w * 16 + lr;
        int do0 = qg * 8;
        float o[8];
#pragma unroll
        for (int r = 0; r < 8; ++r) o[r] = fcb_s[do0 + r];
#pragma unroll
        for (int d = 0; d < 32; ++d) {
            float a = agg_s[orow][d];
#pragma unroll
            for (int r = 0; r < 8; ++r) o[r] = fmaf(a, fcw_s[do0 + r][d], o[r]);
        }
        float4 v0 = make_float4(fmaxf(o[0], 0.f), fmaxf(o[1], 0.f), fmaxf(o[2], 0.f), fmaxf(o[3], 0.f));
        float4 v1 = make_float4(fmaxf(o[4], 0.f), fmaxf(o[5], 0.f), fmaxf(o[6], 0.f), fmaxf(o[7], 0.f));
        float* op = out0 + ((size_t)b * N + it * 64 + orow) * (NH * DOUT) + h * DOUT + do0;
        *(float4*)op = v0;
        *(float4*)(op + 4) = v1;
    }
}

extern "C" void kernel_launch(void* const* d_in, const int* in_sizes, int n_in,
                              void* d_out, int out_size, void* d_ws, size_t ws_size,
                              hipStream_t stream) {
    const float* x = (const float*)d_in[0];
    const int* adj = (const int*)d_in[1];
    const float* att_w = (const float*)d_in[2];
    const float* fc_w = (const float*)d_in[3];
    const float* fc_b = (const float*)d_in[4];

    // Workspace layout (non-overlapping, verified):
    //   adjb  [0,        2097152)   2 MB
    //   xi    [2097152,  2359296)   256 KB
    //   xj    [2359296,  2621440)   256 KB
    //   srow  [2621440,  2883584)   256 KB
    //   xhB   [2883584,  7077888)   4 MB   (srow end == xhB start; no overlap)
    unsigned char* ws = (unsigned char*)d_ws;
    unsigned char* adjb = ws;
    unsigned* adjp = (unsigned*)ws;
    float* xi = (float*)(ws + 2097152);
    float* xj = (float*)(ws + 2359296);
    float* srow = (float*)(ws + 2621440);
    unsigned short* xhB = (unsigned short*)(ws + 2883584);

    float* out0 = (float*)d_out;
    float* att = out0 + (size_t)BATCH * N * NH * DOUT;

    // prep blocks (0..255) first so they start immediately; pack blocks follow
    k_prep_pack<<<256 + (BATCH * N * N) / 8 / 256, 256, 0, stream>>>(x, att_w, adj, xi, xj, xhB, adjb);
    k_rowsum<<<32 * 32, 256, 0, stream>>>(adjp, xi, xj, srow);
    k_main<<<32 * 32, 256, 0, stream>>>(adjp, xi, xj, srow, xhB, fc_w, fc_b, out0, att);
}

// Round 6
// 181.825 us; speedup vs baseline: 1.2374x; 1.2374x over previous
//
#include <hip/hip_runtime.h>
#include <cstdint>

#define N 2048
#define NH 8
#define DI 32
#define DOUT 32
#define BATCH 4
#define LOG2E 1.44269504088896340736f

typedef float f32x4 __attribute__((ext_vector_type(4)));
typedef __bf16 bf16x8 __attribute__((ext_vector_type(8)));

__device__ __forceinline__ unsigned short f2bf(float f) {
    unsigned u = __float_as_uint(f);
    u = u + 0x7fffu + ((u >> 16) & 1u);
    return (unsigned short)(u >> 16);
}

// Deterministic per-block row-max of xj_s[0..2047]. Max is order-independent
// in value, so k_sum and k_store get identical M for the same g.
__device__ __forceinline__ float rowmax2048(const float* xj_s, int tid, float* red) {
    float m = fmaxf(fmaxf(xj_s[tid], xj_s[tid + 256]),
                    fmaxf(xj_s[tid + 512], xj_s[tid + 768]));
    m = fmaxf(m, fmaxf(fmaxf(xj_s[tid + 1024], xj_s[tid + 1280]),
                       fmaxf(xj_s[tid + 1536], xj_s[tid + 1792])));
#pragma unroll
    for (int off = 32; off >= 1; off >>= 1) m = fmaxf(m, __shfl_xor(m, off, 64));
    if ((tid & 63) == 0) red[tid >> 6] = m;
    __syncthreads();
    return fmaxf(fmaxf(red[0], red[1]), fmaxf(red[2], red[3]));
}

// ---------------- K1: fused prep (blocks 0..255) + pack (blocks 256..8447) ----------------
__global__ __launch_bounds__(256) void k_prep_pack(
    const float* __restrict__ x, const float* __restrict__ att_w,
    const int* __restrict__ adj, float* __restrict__ xi, float* __restrict__ xj,
    unsigned short* __restrict__ xhB, unsigned char* __restrict__ adjb) {
    if (blockIdx.x >= 256) {
        int t = (blockIdx.x - 256) * 256 + threadIdx.x;
        const int4* p = (const int4*)adj + (size_t)t * 2;
        int4 a = p[0], b = p[1];
        unsigned byte = (a.x != 0) | ((a.y != 0) << 1) | ((a.z != 0) << 2) | ((a.w != 0) << 3)
                      | ((b.x != 0) << 4) | ((b.y != 0) << 5) | ((b.z != 0) << 6) | ((b.w != 0) << 7);
        adjb[t] = (unsigned char)byte;
        return;
    }
    int g = blockIdx.x >> 3, chunk = blockIdx.x & 7;
    int b = g >> 3, h = g & 7;
    __shared__ float aw[2 * DI];
    if (threadIdx.x < 2 * DI) aw[threadIdx.x] = att_w[threadIdx.x];
    __syncthreads();

    int i = chunk * 256 + threadIdx.x;
    const float* xr = x + ((size_t)b * N + i) * (NH * DI) + h * DI;
    float si = 0.f, sj = 0.f;
#pragma unroll
    for (int d = 0; d < DI; ++d) {
        float v = xr[d];
        si += v * aw[d];
        sj += v * aw[DI + d];
    }
    xi[g * N + i] = si;
    xj[g * N + i] = sj;

    // B-fragment layout for mfma_f32_16x16x32_bf16 (verified round 1):
    // tiles indexed [g][jt(64)][dh(2)][lane(64)][r(8)]
    for (int t = 0; t < 4; ++t) {
        int item = t * 256 + threadIdx.x;
        int lane = item & 63;
        int dh = (item >> 6) & 1;
        int jt = chunk * 8 + (item >> 7);
        int d = dh * 16 + (lane & 15);
        int j0 = jt * 32 + (lane >> 4) * 8;
        union { unsigned short u[8]; uint4 v; } f;
#pragma unroll
        for (int r = 0; r < 8; ++r) {
            float v = x[((size_t)b * N + j0 + r) * (NH * DI) + h * DI + d];
            f.u[r] = f2bf(v);
        }
        *(uint4*)(xhB + ((((size_t)g * 64 + jt) * 2 + dh) * 64 + lane) * 8) = f.v;
    }
}

// ---------------- K2: denominator + MFMA agg + out0 epilogue (NO att stores) ----------------
// xhB loads run against a store-free L2 -> stay L2-resident (the R1-pass1 regime).
// MFMA consumes UNNORMALIZED e (bf16 in [0,1]); acc scaled by 1/ssum in epilogue.
__global__ __launch_bounds__(256, 4) void k_sum(
    const unsigned* __restrict__ adjp, const float* __restrict__ xi_g,
    const float* __restrict__ xj_g, const unsigned short* __restrict__ xhB,
    const float* __restrict__ fc_w, const float* __restrict__ fc_b,
    float* __restrict__ srow, float* __restrict__ out0) {
    int g = blockIdx.x >> 5;
    int it = blockIdx.x & 31;
    int b = g >> 3, h = g & 7, ab = g & 3;
    int tid = threadIdx.x;
    int w = tid >> 6, l = tid & 63;
    int qg = l >> 4, lr = l & 15;

    __shared__ float xj_s[N];
    __shared__ unsigned adj_s[64][65];
    __shared__ float red[4];
    __shared__ float s_s[64];
    __shared__ float fcw_s[32][33];
    __shared__ float fcb_s[32];
    __shared__ float agg_s[64][33];

    {
        const float4* src = (const float4*)(xj_g + (size_t)g * N);
        float4* dst = (float4*)xj_s;
        dst[tid] = src[tid];
        dst[256 + tid] = src[256 + tid];
    }
    {
        int row = tid >> 2, seg = tid & 3;
        const uint4* src = (const uint4*)(adjp + (((size_t)ab * N) + it * 64 + row) * 64 + seg * 16);
#pragma unroll
        for (int q = 0; q < 4; ++q) {
            uint4 v = src[q];
            unsigned* dst = &adj_s[row][seg * 16 + q * 4];
            dst[0] = v.x; dst[1] = v.y; dst[2] = v.z; dst[3] = v.w;
        }
    }
    if (tid < 32) fcb_s[tid] = fc_b[tid];
    {
        float4 v = ((const float4*)fc_w)[tid];
        int row = tid >> 3, c0 = (tid & 7) * 4;
        fcw_s[row][c0 + 0] = v.x; fcw_s[row][c0 + 1] = v.y;
        fcw_s[row][c0 + 2] = v.z; fcw_s[row][c0 + 3] = v.w;
    }
    __syncthreads();
    float xjm = rowmax2048(xj_s, tid, red);

    int iloc = w * 16 + lr;
    int i = it * 64 + iloc;
    float xiv = xi_g[(size_t)g * N + i];
    float vM = xiv + xjm;
    float M = fmaxf(vM, 0.01f * vM);
    float nMl = -M * LOG2E;

    f32x4 acc0 = {0.f, 0.f, 0.f, 0.f}, acc1 = {0.f, 0.f, 0.f, 0.f};
    float ssum = 0.f;
    const unsigned short* xb = xhB + (size_t)g * 64 * 2 * 64 * 8;

    const bf16x8* bp0 = (const bf16x8*)(xb + ((size_t)l) * 8);
    bf16x8 b0 = bp0[0];
    bf16x8 b1 = bp0[64];

    for (int jt = 0; jt < 64; ++jt) {
        int jn = (jt + 1) & 63;
        const bf16x8* bpn = (const bf16x8*)(xb + (((size_t)jn * 2) * 64 + l) * 8);
        bf16x8 nb0 = bpn[0];
        bf16x8 nb1 = bpn[64];

        unsigned byte = (adj_s[iloc][jt] >> (qg * 8)) & 0xffu;
        int j0 = jt * 32 + qg * 8;
        f32x4 xa = *(const f32x4*)&xj_s[j0];
        f32x4 xb4 = *(const f32x4*)&xj_s[j0 + 4];
        bf16x8 af;
#pragma unroll
        for (int r = 0; r < 8; ++r) {
            float xjv = (r < 4) ? xa[r] : xb4[r - 4];
            float sc = xiv + xjv;
            sc = fmaxf(sc, 0.01f * sc);
            float p = __builtin_amdgcn_exp2f(fmaf(sc, LOG2E, nMl));
            float e = ((byte >> r) & 1u) ? p : 0.f;
            ssum += e;
            af[r] = (__bf16)e;
        }
        acc0 = __builtin_amdgcn_mfma_f32_16x16x32_bf16(af, b0, acc0, 0, 0, 0);
        acc1 = __builtin_amdgcn_mfma_f32_16x16x32_bf16(af, b1, acc1, 0, 0, 0);
        b0 = nb0;
        b1 = nb1;
    }

    ssum += __shfl_xor(ssum, 16, 64);
    ssum += __shfl_xor(ssum, 32, 64);
    if (qg == 0) {
        s_s[iloc] = ssum;
        srow[(size_t)g * N + i] = ssum;
    }
    __syncthreads();

    // epilogue: normalize acc, out = relu(agg @ fc_w^T + fc_b)
    {
        int r0 = w * 16 + qg * 4;
#pragma unroll
        for (int r = 0; r < 4; ++r) {
            float inv = 1.0f / s_s[r0 + r];
            agg_s[r0 + r][lr] = acc0[r] * inv;
            agg_s[r0 + r][16 + lr] = acc1[r] * inv;
        }
    }
    __syncthreads();
    {
        int orow = w * 16 + lr;
        int do0 = qg * 8;
        float o[8];
#pragma unroll
        for (int r = 0; r < 8; ++r) o[r] = fcb_s[do0 + r];
#pragma unroll
        for (int d = 0; d < 32; ++d) {
            float a = agg_s[orow][d];
#pragma unroll
            for (int r = 0; r < 8; ++r) o[r] = fmaf(a, fcw_s[do0 + r][d], o[r]);
        }
        float4 v0 = make_float4(fmaxf(o[0], 0.f), fmaxf(o[1], 0.f), fmaxf(o[2], 0.f), fmaxf(o[3], 0.f));
        float4 v1 = make_float4(fmaxf(o[4], 0.f), fmaxf(o[5], 0.f), fmaxf(o[6], 0.f), fmaxf(o[7], 0.f));
        float* op = out0 + ((size_t)b * N + it * 64 + orow) * (NH * DOUT) + h * DOUT + do0;
        *(float4*)op = v0;
        *(float4*)(op + 4) = v1;
    }
}

// ---------------- K3: pure normalize + att store stream (NO loads in loop) ----------------
__global__ __launch_bounds__(256, 4) void k_store(
    const unsigned* __restrict__ adjp, const float* __restrict__ xi_g,
    const float* __restrict__ xj_g, const float* __restrict__ srow,
    float* __restrict__ att) {
    int g = blockIdx.x >> 5;
    int it = blockIdx.x & 31;
    int ab = g & 3;
    int tid = threadIdx.x;
    int w = tid >> 6, l = tid & 63;
    int qg = l >> 4, lr = l & 15;

    __shared__ float xj_s[N];
    __shared__ unsigned adj_s[64][65];
    __shared__ float red[4];

    {
        const float4* src = (const float4*)(xj_g + (size_t)g * N);
        float4* dst = (float4*)xj_s;
        dst[tid] = src[tid];
        dst[256 + tid] = src[256 + tid];
    }
    {
        int row = tid >> 2, seg = tid & 3;
        const uint4* src = (const uint4*)(adjp + (((size_t)ab * N) + it * 64 + row) * 64 + seg * 16);
#pragma unroll
        for (int q = 0; q < 4; ++q) {
            uint4 v = src[q];
            unsigned* dst = &adj_s[row][seg * 16 + q * 4];
            dst[0] = v.x; dst[1] = v.y; dst[2] = v.z; dst[3] = v.w;
        }
    }
    __syncthreads();
    float xjm = rowmax2048(xj_s, tid, red);   // identical value to k_sum's M

    int iloc = w * 16 + lr;
    int i = it * 64 + iloc;
    float xiv = xi_g[(size_t)g * N + i];
    float vM = xiv + xjm;
    float M = fmaxf(vM, 0.01f * vM);
    float nMl = -M * LOG2E;
    float invA = 1.0f / srow[(size_t)g * N + i];

    float* arow = att + ((size_t)g * N + i) * N;
    for (int jt = 0; jt < 64; ++jt) {
        unsigned byte = (adj_s[iloc][jt] >> (qg * 8)) & 0xffu;
        int j0 = jt * 32 + qg * 8;
        f32x4 xa = *(const f32x4*)&xj_s[j0];
        f32x4 xb4 = *(const f32x4*)&xj_s[j0 + 4];
        f32x4 o0, o1;
#pragma unroll
        for (int r = 0; r < 8; ++r) {
            float xjv = (r < 4) ? xa[r] : xb4[r - 4];
            float sc = xiv + xjv;
            sc = fmaxf(sc, 0.01f * sc);
            float p = __builtin_amdgcn_exp2f(fmaf(sc, LOG2E, nMl)) * invA;
            float av = ((byte >> r) & 1u) ? p : 0.f;
            if (r < 4) o0[r] = av; else o1[r - 4] = av;
        }
        *(f32x4*)&arow[j0] = o0;
        *(f32x4*)&arow[j0 + 4] = o1;
    }
}

extern "C" void kernel_launch(void* const* d_in, const int* in_sizes, int n_in,
                              void* d_out, int out_size, void* d_ws, size_t ws_size,
                              hipStream_t stream) {
    const float* x = (const float*)d_in[0];
    const int* adj = (const int*)d_in[1];
    const float* att_w = (const float*)d_in[2];
    const float* fc_w = (const float*)d_in[3];
    const float* fc_b = (const float*)d_in[4];

    // Workspace layout (non-overlapping):
    //   adjb  [0,        2097152)   2 MB
    //   xi    [2097152,  2359296)   256 KB
    //   xj    [2359296,  2621440)   256 KB
    //   srow  [2621440,  2883584)   256 KB
    //   xhB   [2883584,  7077888)   4 MB
    unsigned char* ws = (unsigned char*)d_ws;
    unsigned char* adjb = ws;
    unsigned* adjp = (unsigned*)ws;
    float* xi = (float*)(ws + 2097152);
    float* xj = (float*)(ws + 2359296);
    float* srow = (float*)(ws + 2621440);
    unsigned short* xhB = (unsigned short*)(ws + 2883584);

    float* out0 = (float*)d_out;
    float* att = out0 + (size_t)BATCH * N * NH * DOUT;

    k_prep_pack<<<256 + (BATCH * N * N) / 8 / 256, 256, 0, stream>>>(x, att_w, adj, xi, xj, xhB, adjb);
    k_sum<<<32 * 32, 256, 0, stream>>>(adjp, xi, xj, xhB, fc_w, fc_b, srow, out0);
    k_store<<<32 * 32, 256, 0, stream>>>(adjp, xi, xj, srow, att);
}

// Round 7
// 175.239 us; speedup vs baseline: 1.2839x; 1.0376x over previous
//
#include <hip/hip_runtime.h>
#include <cstdint>

#define N 2048
#define NH 8
#define DI 32
#define DOUT 32
#define BATCH 4
#define LOG2E 1.44269504088896340736f

typedef float f32x4 __attribute__((ext_vector_type(4)));
typedef __bf16 bf16x8 __attribute__((ext_vector_type(8)));

__device__ __forceinline__ unsigned short f2bf(float f) {
    unsigned u = __float_as_uint(f);
    u = u + 0x7fffu + ((u >> 16) & 1u);
    return (unsigned short)(u >> 16);
}

// Deterministic per-block row-max of xj_s[0..2047]; value is order-independent.
__device__ __forceinline__ float rowmax2048(const float* xj_s, int tid, float* red) {
    float m = fmaxf(fmaxf(xj_s[tid], xj_s[tid + 256]),
                    fmaxf(xj_s[tid + 512], xj_s[tid + 768]));
    m = fmaxf(m, fmaxf(fmaxf(xj_s[tid + 1024], xj_s[tid + 1280]),
                       fmaxf(xj_s[tid + 1536], xj_s[tid + 1792])));
#pragma unroll
    for (int off = 32; off >= 1; off >>= 1) m = fmaxf(m, __shfl_xor(m, off, 64));
    if ((tid & 63) == 0) red[tid >> 6] = m;
    __syncthreads();
    return fmaxf(fmaxf(red[0], red[1]), fmaxf(red[2], red[3]));
}

// ---------------- K1: fused prep (blocks 0..255) + pack (blocks 256..8447) ----------------
__global__ __launch_bounds__(256) void k_prep_pack(
    const float* __restrict__ x, const float* __restrict__ att_w,
    const int* __restrict__ adj, float* __restrict__ xi, float* __restrict__ xj,
    unsigned short* __restrict__ xhB, unsigned char* __restrict__ adjb) {
    if (blockIdx.x >= 256) {
        int t = (blockIdx.x - 256) * 256 + threadIdx.x;
        const int4* p = (const int4*)adj + (size_t)t * 2;
        int4 a = p[0], b = p[1];
        unsigned byte = (a.x != 0) | ((a.y != 0) << 1) | ((a.z != 0) << 2) | ((a.w != 0) << 3)
                      | ((b.x != 0) << 4) | ((b.y != 0) << 5) | ((b.z != 0) << 6) | ((b.w != 0) << 7);
        adjb[t] = (unsigned char)byte;
        return;
    }
    int g = blockIdx.x >> 3, chunk = blockIdx.x & 7;
    int b = g >> 3, h = g & 7;
    __shared__ float aw[2 * DI];
    if (threadIdx.x < 2 * DI) aw[threadIdx.x] = att_w[threadIdx.x];
    __syncthreads();

    int i = chunk * 256 + threadIdx.x;
    const float* xr = x + ((size_t)b * N + i) * (NH * DI) + h * DI;
    float si = 0.f, sj = 0.f;
#pragma unroll
    for (int d = 0; d < DI; ++d) {
        float v = xr[d];
        si += v * aw[d];
        sj += v * aw[DI + d];
    }
    xi[g * N + i] = si;
    xj[g * N + i] = sj;

    // B-fragment layout for mfma_f32_16x16x32_bf16 (verified round 1):
    // tiles indexed [g][jt(64)][dh(2)][lane(64)][r(8)]
    for (int t = 0; t < 4; ++t) {
        int item = t * 256 + threadIdx.x;
        int lane = item & 63;
        int dh = (item >> 6) & 1;
        int jt = chunk * 8 + (item >> 7);
        int d = dh * 16 + (lane & 15);
        int j0 = jt * 32 + (lane >> 4) * 8;
        union { unsigned short u[8]; uint4 v; } f;
#pragma unroll
        for (int r = 0; r < 8; ++r) {
            float v = x[((size_t)b * N + j0 + r) * (NH * DI) + h * DI + d];
            f.u[r] = f2bf(v);
        }
        *(uint4*)(xhB + ((((size_t)g * 64 + jt) * 2 + dh) * 64 + lane) * 8) = f.v;
    }
}

// ---------------- K2: fused role-split main kernel ----------------
// Even blocks = store role (self-sum sweep, then dense att stores; zero loop loads).
// Odd blocks  = sum role (exp sweep + MFMA + out0 epilogue; zero loop stores).
// Roles live in different waves -> separate vmcnt queues; write pipe fed throughout.
__global__ __launch_bounds__(256, 4) void k_fused(
    const unsigned* __restrict__ adjp, const float* __restrict__ xi_g,
    const float* __restrict__ xj_g, const unsigned short* __restrict__ xhB,
    const float* __restrict__ fc_w, const float* __restrict__ fc_b,
    float* __restrict__ out0, float* __restrict__ att) {
    int role = blockIdx.x & 1;
    int sid = blockIdx.x >> 1;
    int g = sid >> 5, it = sid & 31;
    int b = g >> 3, h = g & 7, ab = g & 3;
    int tid = threadIdx.x;
    int w = tid >> 6, l = tid & 63;
    int qg = l >> 4, lr = l & 15;

    __shared__ float xj_s[N];
    __shared__ unsigned adj_s[64][65];
    __shared__ float red[4];
    __shared__ float s_s[64];
    __shared__ float fcw_s[32][33];
    __shared__ float fcb_s[32];
    __shared__ float agg_s[64][33];

    {
        const float4* src = (const float4*)(xj_g + (size_t)g * N);
        float4* dst = (float4*)xj_s;
        dst[tid] = src[tid];
        dst[256 + tid] = src[256 + tid];
    }
    {
        int row = tid >> 2, seg = tid & 3;
        const uint4* src = (const uint4*)(adjp + (((size_t)ab * N) + it * 64 + row) * 64 + seg * 16);
#pragma unroll
        for (int q = 0; q < 4; ++q) {
            uint4 v = src[q];
            unsigned* dst = &adj_s[row][seg * 16 + q * 4];
            dst[0] = v.x; dst[1] = v.y; dst[2] = v.z; dst[3] = v.w;
        }
    }
    if (role == 1) {
        if (tid < 32) fcb_s[tid] = fc_b[tid];
        float4 v = ((const float4*)fc_w)[tid];
        int row = tid >> 3, c0 = (tid & 7) * 4;
        fcw_s[row][c0 + 0] = v.x; fcw_s[row][c0 + 1] = v.y;
        fcw_s[row][c0 + 2] = v.z; fcw_s[row][c0 + 3] = v.w;
    }
    __syncthreads();
    float xjm = rowmax2048(xj_s, tid, red);

    int iloc = w * 16 + lr;
    int i = it * 64 + iloc;
    float xiv = xi_g[(size_t)g * N + i];
    float vM = xiv + xjm;
    float M = fmaxf(vM, 0.01f * vM);
    float nMl = -M * LOG2E;

    if (role == 1) {
        // ================= SUM ROLE: denominator + MFMA agg + out0 =================
        f32x4 acc0 = {0.f, 0.f, 0.f, 0.f}, acc1 = {0.f, 0.f, 0.f, 0.f};
        float ssum = 0.f;
        const unsigned short* xb = xhB + (size_t)g * 64 * 2 * 64 * 8;

        const bf16x8* bp0 = (const bf16x8*)(xb + ((size_t)l) * 8);
        bf16x8 b0 = bp0[0];
        bf16x8 b1 = bp0[64];

        for (int jt = 0; jt < 64; ++jt) {
            int jn = (jt + 1) & 63;
            const bf16x8* bpn = (const bf16x8*)(xb + (((size_t)jn * 2) * 64 + l) * 8);
            bf16x8 nb0 = bpn[0];
            bf16x8 nb1 = bpn[64];

            unsigned byte = (adj_s[iloc][jt] >> (qg * 8)) & 0xffu;
            int j0 = jt * 32 + qg * 8;
            f32x4 xa = *(const f32x4*)&xj_s[j0];
            f32x4 xb4 = *(const f32x4*)&xj_s[j0 + 4];
            bf16x8 af;
#pragma unroll
            for (int r = 0; r < 8; ++r) {
                float xjv = (r < 4) ? xa[r] : xb4[r - 4];
                float sc = xiv + xjv;
                sc = fmaxf(sc, 0.01f * sc);
                float p = __builtin_amdgcn_exp2f(fmaf(sc, LOG2E, nMl));
                float e = ((byte >> r) & 1u) ? p : 0.f;
                ssum += e;
                af[r] = (__bf16)e;
            }
            acc0 = __builtin_amdgcn_mfma_f32_16x16x32_bf16(af, b0, acc0, 0, 0, 0);
            acc1 = __builtin_amdgcn_mfma_f32_16x16x32_bf16(af, b1, acc1, 0, 0, 0);
            b0 = nb0;
            b1 = nb1;
        }

        ssum += __shfl_xor(ssum, 16, 64);
        ssum += __shfl_xor(ssum, 32, 64);
        if (qg == 0) s_s[iloc] = ssum;
        __syncthreads();

        {
            int r0 = w * 16 + qg * 4;
#pragma unroll
            for (int r = 0; r < 4; ++r) {
                float inv = 1.0f / s_s[r0 + r];
                agg_s[r0 + r][lr] = acc0[r] * inv;
                agg_s[r0 + r][16 + lr] = acc1[r] * inv;
            }
        }
        __syncthreads();
        {
            int orow = w * 16 + lr;
            int do0 = qg * 8;
            float o[8];
#pragma unroll
            for (int r = 0; r < 8; ++r) o[r] = fcb_s[do0 + r];
#pragma unroll
            for (int d = 0; d < 32; ++d) {
                float a = agg_s[orow][d];
#pragma unroll
                for (int r = 0; r < 8; ++r) o[r] = fmaf(a, fcw_s[do0 + r][d], o[r]);
            }
            float4 v0 = make_float4(fmaxf(o[0], 0.f), fmaxf(o[1], 0.f), fmaxf(o[2], 0.f), fmaxf(o[3], 0.f));
            float4 v1 = make_float4(fmaxf(o[4], 0.f), fmaxf(o[5], 0.f), fmaxf(o[6], 0.f), fmaxf(o[7], 0.f));
            float* op = out0 + ((size_t)b * N + it * 64 + orow) * (NH * DOUT) + h * DOUT + do0;
            *(float4*)op = v0;
            *(float4*)(op + 4) = v1;
        }
        return;
    }

    // ================= STORE ROLE =================
    // Sweep 1: per-row denominators (row-per-lane mapping, 2 shfls)
    {
        float ssum = 0.f;
        for (int jt = 0; jt < 64; ++jt) {
            unsigned byte = (adj_s[iloc][jt] >> (qg * 8)) & 0xffu;
            int j0 = jt * 32 + qg * 8;
            f32x4 xa = *(const f32x4*)&xj_s[j0];
            f32x4 xb4 = *(const f32x4*)&xj_s[j0 + 4];
#pragma unroll
            for (int r = 0; r < 8; ++r) {
                float xjv = (r < 4) ? xa[r] : xb4[r - 4];
                float sc = xiv + xjv;
                sc = fmaxf(sc, 0.01f * sc);
                float p = __builtin_amdgcn_exp2f(fmaf(sc, LOG2E, nMl));
                ssum += ((byte >> r) & 1u) ? p : 0.f;
            }
        }
        ssum += __shfl_xor(ssum, 16, 64);
        ssum += __shfl_xor(ssum, 32, 64);
        if (qg == 0) s_s[iloc] = ssum;
    }
    __syncthreads();

    // Sweep 2: dense stores — wave w owns rows 16w..16w+15; per (row, seg) each
    // lane writes 16 B at byte 16*l of a 2 KB segment -> contiguous 1 KB per instr.
    for (int rr = 0; rr < 16; ++rr) {
        int row = w * 16 + rr;
        float xiv2 = xi_g[(size_t)g * N + it * 64 + row];   // broadcast (L1)
        float vM2 = xiv2 + xjm;
        float M2 = fmaxf(vM2, 0.01f * vM2);
        float nMl2 = -M2 * LOG2E;
        float invA = 1.0f / s_s[row];
        float* arow = att + ((size_t)g * N + it * 64 + row) * N;
        const unsigned* adjrow = adj_s[row];
        int sh = 4 * (l & 7);
        int wi = l >> 3;
#pragma unroll
        for (int seg = 0; seg < 4; ++seg) {
            int j0 = seg * 512 + 4 * l;
            unsigned nib0 = (adjrow[seg * 16 + wi] >> sh) & 0xfu;
            unsigned nib1 = (adjrow[seg * 16 + 8 + wi] >> sh) & 0xfu;
            f32x4 xa = *(const f32x4*)&xj_s[j0];
            f32x4 xc = *(const f32x4*)&xj_s[j0 + 256];
            f32x4 o0, o1;
#pragma unroll
            for (int k = 0; k < 4; ++k) {
                float s0 = xiv2 + xa[k];
                s0 = fmaxf(s0, 0.01f * s0);
                float p0 = __builtin_amdgcn_exp2f(fmaf(s0, LOG2E, nMl2)) * invA;
                o0[k] = ((nib0 >> k) & 1u) ? p0 : 0.f;
                float s1 = xiv2 + xc[k];
                s1 = fmaxf(s1, 0.01f * s1);
                float p1 = __builtin_amdgcn_exp2f(fmaf(s1, LOG2E, nMl2)) * invA;
                o1[k] = ((nib1 >> k) & 1u) ? p1 : 0.f;
            }
            *(f32x4*)&arow[j0] = o0;
            *(f32x4*)&arow[j0 + 256] = o1;
        }
    }
}

extern "C" void kernel_launch(void* const* d_in, const int* in_sizes, int n_in,
                              void* d_out, int out_size, void* d_ws, size_t ws_size,
                              hipStream_t stream) {
    const float* x = (const float*)d_in[0];
    const int* adj = (const int*)d_in[1];
    const float* att_w = (const float*)d_in[2];
    const float* fc_w = (const float*)d_in[3];
    const float* fc_b = (const float*)d_in[4];

    // Workspace layout (non-overlapping):
    //   adjb  [0,        2097152)   2 MB
    //   xi    [2097152,  2359296)   256 KB
    //   xj    [2359296,  2621440)   256 KB
    //   xhB   [2621440,  6815744)   4 MB
    unsigned char* ws = (unsigned char*)d_ws;
    unsigned char* adjb = ws;
    unsigned* adjp = (unsigned*)ws;
    float* xi = (float*)(ws + 2097152);
    float* xj = (float*)(ws + 2359296);
    unsigned short* xhB = (unsigned short*)(ws + 2621440);

    float* out0 = (float*)d_out;
    float* att = out0 + (size_t)BATCH * N * NH * DOUT;

    k_prep_pack<<<256 + (BATCH * N * N) / 8 / 256, 256, 0, stream>>>(x, att_w, adj, xi, xj, xhB, adjb);
    k_fused<<<2048, 256, 0, stream>>>(adjp, xi, xj, xhB, fc_w, fc_b, out0, att);
}

// Round 8
// 168.401 us; speedup vs baseline: 1.3360x; 1.0406x over previous
//
#include <hip/hip_runtime.h>
#include <cstdint>

#define N 2048
#define NH 8
#define DI 32
#define DOUT 32
#define BATCH 4
#define LOG2E 1.44269504088896340736f

typedef float f32x4 __attribute__((ext_vector_type(4)));
typedef __bf16 bf16x8 __attribute__((ext_vector_type(8)));

__device__ __forceinline__ unsigned short f2bf(float f) {
    unsigned u = __float_as_uint(f);
    u = u + 0x7fffu + ((u >> 16) & 1u);
    return (unsigned short)(u >> 16);
}

// ---------------- K1: fused prep (blocks 0..255) + pack (blocks 256..8447) ----------------
__global__ __launch_bounds__(256) void k_prep_pack(
    const float* __restrict__ x, const float* __restrict__ att_w,
    const int* __restrict__ adj, float* __restrict__ xi, float* __restrict__ xj,
    unsigned short* __restrict__ xhB, unsigned char* __restrict__ adjb) {
    if (blockIdx.x >= 256) {
        int t = (blockIdx.x - 256) * 256 + threadIdx.x;
        const int4* p = (const int4*)adj + (size_t)t * 2;
        int4 a = p[0], b = p[1];
        unsigned byte = (a.x != 0) | ((a.y != 0) << 1) | ((a.z != 0) << 2) | ((a.w != 0) << 3)
                      | ((b.x != 0) << 4) | ((b.y != 0) << 5) | ((b.z != 0) << 6) | ((b.w != 0) << 7);
        adjb[t] = (unsigned char)byte;
        return;
    }
    int g = blockIdx.x >> 3, chunk = blockIdx.x & 7;
    int b = g >> 3, h = g & 7;
    __shared__ float aw[2 * DI];
    if (threadIdx.x < 2 * DI) aw[threadIdx.x] = att_w[threadIdx.x];
    __syncthreads();

    int i = chunk * 256 + threadIdx.x;
    const float* xr = x + ((size_t)b * N + i) * (NH * DI) + h * DI;
    float si = 0.f, sj = 0.f;
#pragma unroll
    for (int d = 0; d < DI; ++d) {
        float v = xr[d];
        si += v * aw[d];
        sj += v * aw[DI + d];
    }
    xi[g * N + i] = si;
    xj[g * N + i] = sj;

    // B-fragment layout for mfma_f32_16x16x32_bf16 (verified round 1):
    // tiles indexed [g][jt(64)][dh(2)][lane(64)][r(8)]
    for (int t = 0; t < 4; ++t) {
        int item = t * 256 + threadIdx.x;
        int lane = item & 63;
        int dh = (item >> 6) & 1;
        int jt = chunk * 8 + (item >> 7);
        int d = dh * 16 + (lane & 15);
        int j0 = jt * 32 + (lane >> 4) * 8;
        union { unsigned short u[8]; uint4 v; } f;
#pragma unroll
        for (int r = 0; r < 8; ++r) {
            float v = x[((size_t)b * N + j0 + r) * (NH * DI) + h * DI + d];
            f.u[r] = f2bf(v);
        }
        *(uint4*)(xhB + ((((size_t)g * 64 + jt) * 2 + dh) * 64 + lane) * 8) = f.v;
    }
}

// ---------------- K2: fused role-split main kernel (factorized exp via LDS tables) ----------------
// e = exp(lrelu(xi+xj)-M) = pos ? A1*B1[j] : A2*B2[j], pos <=> B1[j] >= exp2(-xi*L).
// B1/B2 are per-g tables in LDS (16 KB); A1/A2 per-row scalars (invA folded in store sweep).
// Even blocks = store role (sweep1 denominators, sweep2 dense att stores; no loop loads).
// Odd blocks  = sum role (MFMA sweep + out0 epilogue; no loop stores).
__global__ __launch_bounds__(256, 4) void k_fused(
    const unsigned* __restrict__ adjp, const float* __restrict__ xi_g,
    const float* __restrict__ xj_g, const unsigned short* __restrict__ xhB,
    const float* __restrict__ fc_w, const float* __restrict__ fc_b,
    float* __restrict__ out0, float* __restrict__ att) {
    int role = blockIdx.x & 1;
    int sid = blockIdx.x >> 1;
    int g = sid >> 5, it = sid & 31;
    int b = g >> 3, h = g & 7, ab = g & 3;
    int tid = threadIdx.x;
    int w = tid >> 6, l = tid & 63;
    int qg = l >> 4, lr = l & 15;

    // LDS layout (floats): B1[2048] | B2[2048] | ADJ 64x65 (aliased by AGG 64x33
    // after the sum loop) | FCW 32x33 | FCB 32 | SS 64 | RED 4   => 9412 f = 36.8 KB
    __shared__ alignas(16) float SM[9412];
    float* B1s = SM;
    float* B2s = SM + 2048;
    unsigned* ADJ = (unsigned*)(SM + 4096);
    float* AGG = SM + 4096;
    float* FCW = SM + 8256;
    float* FCB = SM + 9312;
    float* SS  = SM + 9344;
    float* RED = SM + 9408;

    // ---- build B1/B2 tables + per-thread max of xj ----
    float mymax;
    {
        int j8 = tid * 8;
        const float* xjr = xj_g + (size_t)g * N + j8;
        f32x4 xa = *(const f32x4*)xjr;
        f32x4 xc = *(const f32x4*)(xjr + 4);
        f32x4 p1a, p1b, p2a, p2b;
        mymax = -3.4e38f;
#pragma unroll
        for (int k = 0; k < 4; ++k) {
            float v = xa[k];
            p1a[k] = __builtin_amdgcn_exp2f(v * LOG2E);
            p2a[k] = __builtin_amdgcn_exp2f(0.01f * v * LOG2E);
            mymax = fmaxf(mymax, v);
        }
#pragma unroll
        for (int k = 0; k < 4; ++k) {
            float v = xc[k];
            p1b[k] = __builtin_amdgcn_exp2f(v * LOG2E);
            p2b[k] = __builtin_amdgcn_exp2f(0.01f * v * LOG2E);
            mymax = fmaxf(mymax, v);
        }
        *(f32x4*)&B1s[j8] = p1a; *(f32x4*)&B1s[j8 + 4] = p1b;
        *(f32x4*)&B2s[j8] = p2a; *(f32x4*)&B2s[j8 + 4] = p2b;
    }
    // ---- stage packed adj rows ----
    {
        int row = tid >> 2, seg = tid & 3;
        const uint4* src = (const uint4*)(adjp + (((size_t)ab * N) + it * 64 + row) * 64 + seg * 16);
#pragma unroll
        for (int q = 0; q < 4; ++q) {
            uint4 v = src[q];
            unsigned* dst = &ADJ[row * 65 + seg * 16 + q * 4];
            dst[0] = v.x; dst[1] = v.y; dst[2] = v.z; dst[3] = v.w;
        }
    }
    if (role == 1) {
        if (tid < 32) FCB[tid] = fc_b[tid];
        float4 v = ((const float4*)fc_w)[tid];
        int row = tid >> 3, c0 = (tid & 7) * 4;
        FCW[row * 33 + c0 + 0] = v.x; FCW[row * 33 + c0 + 1] = v.y;
        FCW[row * 33 + c0 + 2] = v.z; FCW[row * 33 + c0 + 3] = v.w;
    }
#pragma unroll
    for (int off = 32; off >= 1; off >>= 1) mymax = fmaxf(mymax, __shfl_xor(mymax, off, 64));
    if ((tid & 63) == 0) RED[tid >> 6] = mymax;
    __syncthreads();
    float xjm = fmaxf(fmaxf(RED[0], RED[1]), fmaxf(RED[2], RED[3]));

    int iloc = w * 16 + lr;
    int i = it * 64 + iloc;
    float xiv = xi_g[(size_t)g * N + i];
    float vM = xiv + xjm;
    float M = fmaxf(vM, 0.01f * vM);
    float A1 = __builtin_amdgcn_exp2f((xiv - M) * LOG2E);
    float A2 = __builtin_amdgcn_exp2f((0.01f * xiv - M) * LOG2E);
    float T  = __builtin_amdgcn_exp2f(-xiv * LOG2E);

    if (role == 1) {
        // ================= SUM ROLE: MFMA agg + denominator + out0 =================
        f32x4 acc0 = {0.f, 0.f, 0.f, 0.f}, acc1 = {0.f, 0.f, 0.f, 0.f};
        float ssum = 0.f;
        const unsigned short* xb = xhB + (size_t)g * 64 * 2 * 64 * 8;

        const bf16x8* bp0 = (const bf16x8*)(xb + ((size_t)l) * 8);
        bf16x8 b0 = bp0[0];
        bf16x8 b1 = bp0[64];

        for (int jt = 0; jt < 64; ++jt) {
            int jn = (jt + 1) & 63;
            const bf16x8* bpn = (const bf16x8*)(xb + (((size_t)jn * 2) * 64 + l) * 8);
            bf16x8 nb0 = bpn[0];
            bf16x8 nb1 = bpn[64];

            unsigned byte = (ADJ[iloc * 65 + jt] >> (qg * 8)) & 0xffu;
            int j0 = jt * 32 + qg * 8;
            f32x4 c1a = *(const f32x4*)&B1s[j0];
            f32x4 c1b = *(const f32x4*)&B1s[j0 + 4];
            f32x4 c2a = *(const f32x4*)&B2s[j0];
            f32x4 c2b = *(const f32x4*)&B2s[j0 + 4];
            bf16x8 af;
#pragma unroll
            for (int r = 0; r < 8; ++r) {
                float b1v = (r < 4) ? c1a[r] : c1b[r - 4];
                float b2v = (r < 4) ? c2a[r] : c2b[r - 4];
                bool pos = b1v >= T;
                float bs = pos ? b1v : b2v;
                float as = pos ? A1 : A2;
                float v = as * bs;
                float e = ((byte >> r) & 1u) ? v : 0.f;
                ssum += e;
                af[r] = (__bf16)e;
            }
            acc0 = __builtin_amdgcn_mfma_f32_16x16x32_bf16(af, b0, acc0, 0, 0, 0);
            acc1 = __builtin_amdgcn_mfma_f32_16x16x32_bf16(af, b1, acc1, 0, 0, 0);
            b0 = nb0;
            b1 = nb1;
        }

        ssum += __shfl_xor(ssum, 16, 64);
        ssum += __shfl_xor(ssum, 32, 64);
        if (qg == 0) SS[iloc] = ssum;
        __syncthreads();   // SS visible + all waves done reading ADJ (AGG aliases it)

        {
            int r0 = w * 16 + qg * 4;
#pragma unroll
            for (int r = 0; r < 4; ++r) {
                float inv = 1.0f / SS[r0 + r];
                AGG[(r0 + r) * 33 + lr] = acc0[r] * inv;
                AGG[(r0 + r) * 33 + 16 + lr] = acc1[r] * inv;
            }
        }
        __syncthreads();
        {
            int orow = w * 16 + lr;
            int do0 = qg * 8;
            float o[8];
#pragma unroll
            for (int r = 0; r < 8; ++r) o[r] = FCB[do0 + r];
#pragma unroll
            for (int d = 0; d < 32; ++d) {
                float a = AGG[orow * 33 + d];
#pragma unroll
                for (int r = 0; r < 8; ++r) o[r] = fmaf(a, FCW[(do0 + r) * 33 + d], o[r]);
            }
            float4 v0 = make_float4(fmaxf(o[0], 0.f), fmaxf(o[1], 0.f), fmaxf(o[2], 0.f), fmaxf(o[3], 0.f));
            float4 v1 = make_float4(fmaxf(o[4], 0.f), fmaxf(o[5], 0.f), fmaxf(o[6], 0.f), fmaxf(o[7], 0.f));
            float* op = out0 + ((size_t)b * N + it * 64 + orow) * (NH * DOUT) + h * DOUT + do0;
            *(float4*)op = v0;
            *(float4*)(op + 4) = v1;
        }
        return;
    }

    // ================= STORE ROLE =================
    // Sweep 1: per-row denominators
    {
        float ssum = 0.f;
        for (int jt = 0; jt < 64; ++jt) {
            unsigned byte = (ADJ[iloc * 65 + jt] >> (qg * 8)) & 0xffu;
            int j0 = jt * 32 + qg * 8;
            f32x4 c1a = *(const f32x4*)&B1s[j0];
            f32x4 c1b = *(const f32x4*)&B1s[j0 + 4];
            f32x4 c2a = *(const f32x4*)&B2s[j0];
            f32x4 c2b = *(const f32x4*)&B2s[j0 + 4];
#pragma unroll
            for (int r = 0; r < 8; ++r) {
                float b1v = (r < 4) ? c1a[r] : c1b[r - 4];
                float b2v = (r < 4) ? c2a[r] : c2b[r - 4];
                bool pos = b1v >= T;
                float v = (pos ? A1 : A2) * (pos ? b1v : b2v);
                ssum += ((byte >> r) & 1u) ? v : 0.f;
            }
        }
        ssum += __shfl_xor(ssum, 16, 64);
        ssum += __shfl_xor(ssum, 32, 64);
        if (qg == 0) SS[iloc] = ssum;
    }
    __syncthreads();

    // Sweep 2: dense stores — wave w owns rows 16w..16w+15; contiguous 1 KB per instr.
    for (int rr = 0; rr < 16; ++rr) {
        int row = w * 16 + rr;
        float xiv2 = xi_g[(size_t)g * N + it * 64 + row];   // broadcast
        float vM2 = xiv2 + xjm;
        float M2 = fmaxf(vM2, 0.01f * vM2);
        float invA = 1.0f / SS[row];
        float A1p = __builtin_amdgcn_exp2f((xiv2 - M2) * LOG2E) * invA;
        float A2p = __builtin_amdgcn_exp2f((0.01f * xiv2 - M2) * LOG2E) * invA;
        float T2  = __builtin_amdgcn_exp2f(-xiv2 * LOG2E);
        float* arow = att + ((size_t)g * N + it * 64 + row) * N;
        const unsigned* adjrow = &ADJ[row * 65];
        int sh = 4 * (l & 7);
        int wi = l >> 3;
#pragma unroll
        for (int seg = 0; seg < 4; ++seg) {
            int j0 = seg * 512 + 4 * l;
            unsigned nib0 = (adjrow[seg * 16 + wi] >> sh) & 0xfu;
            unsigned nib1 = (adjrow[seg * 16 + 8 + wi] >> sh) & 0xfu;
            f32x4 b1lo = *(const f32x4*)&B1s[j0];
            f32x4 b2lo = *(const f32x4*)&B2s[j0];
            f32x4 b1hi = *(const f32x4*)&B1s[j0 + 256];
            f32x4 b2hi = *(const f32x4*)&B2s[j0 + 256];
            f32x4 o0, o1;
#pragma unroll
            for (int k = 0; k < 4; ++k) {
                bool p0 = b1lo[k] >= T2;
                float v0 = (p0 ? A1p : A2p) * (p0 ? b1lo[k] : b2lo[k]);
                o0[k] = ((nib0 >> k) & 1u) ? v0 : 0.f;
                bool p1 = b1hi[k] >= T2;
                float v1 = (p1 ? A1p : A2p) * (p1 ? b1hi[k] : b2hi[k]);
                o1[k] = ((nib1 >> k) & 1u) ? v1 : 0.f;
            }
            *(f32x4*)&arow[j0] = o0;
            *(f32x4*)&arow[j0 + 256] = o1;
        }
    }
}

extern "C" void kernel_launch(void* const* d_in, const int* in_sizes, int n_in,
                              void* d_out, int out_size, void* d_ws, size_t ws_size,
                              hipStream_t stream) {
    const float* x = (const float*)d_in[0];
    const int* adj = (const int*)d_in[1];
    const float* att_w = (const float*)d_in[2];
    const float* fc_w = (const float*)d_in[3];
    const float* fc_b = (const float*)d_in[4];

    // Workspace layout (non-overlapping):
    //   adjb  [0,        2097152)   2 MB
    //   xi    [2097152,  2359296)   256 KB
    //   xj    [2359296,  2621440)   256 KB
    //   xhB   [2621440,  6815744)   4 MB
    unsigned char* ws = (unsigned char*)d_ws;
    unsigned char* adjb = ws;
    unsigned* adjp = (unsigned*)ws;
    float* xi = (float*)(ws + 2097152);
    float* xj = (float*)(ws + 2359296);
    unsigned short* xhB = (unsigned short*)(ws + 2621440);

    float* out0 = (float*)d_out;
    float* att = out0 + (size_t)BATCH * N * NH * DOUT;

    k_prep_pack<<<256 + (BATCH * N * N) / 8 / 256, 256, 0, stream>>>(x, att_w, adj, xi, xj, xhB, adjb);
    k_fused<<<2048, 256, 0, stream>>>(adjp, xi, xj, xhB, fc_w, fc_b, out0, att);
}